// Round 1
// baseline (446.282 us; speedup 1.0000x reference)
//
#include <hip/hip_runtime.h>

#define NT 256          // threads per block (4 waves)
#define DIM 4096        // row length
#define VPT 4           // float4 loads per thread
#define EPT 16          // elements per thread

// Order-preserving float->uint key: larger float <=> larger key.
__device__ __forceinline__ unsigned int f2key(float f) {
  unsigned int u = __float_as_uint(f);
  return (u & 0x80000000u) ? ~u : (u | 0x80000000u);
}
__device__ __forceinline__ float key2f(unsigned int k) {
  unsigned int u = (k & 0x80000000u) ? (k & 0x7FFFFFFFu) : ~k;
  return __uint_as_float(u);
}

__global__ __launch_bounds__(NT) void topk_mask_kernel(
    const float* __restrict__ x, float* __restrict__ out, int k) {
  const int row  = blockIdx.x;
  const int tid  = threadIdx.x;
  const int lane = tid & 63;
  const int wv   = tid >> 6;          // wave id 0..3
  const long base = (long)row * DIM;

  // ---- load 16 elements/thread, coalesced float4, convert to keys ----
  const float4* xv = (const float4*)(x + base);
  unsigned int key[EPT];
#pragma unroll
  for (int j = 0; j < VPT; ++j) {
    float4 v = xv[j * NT + tid];
    key[j*4+0] = f2key(v.x);
    key[j*4+1] = f2key(v.y);
    key[j*4+2] = f2key(v.z);
    key[j*4+3] = f2key(v.w);
  }

  __shared__ unsigned int hist[256];
  __shared__ unsigned int wtot[4];
  __shared__ unsigned int sh_selb, sh_sexcl, sh_ce, sh_run;

  unsigned int k_rem = (unsigned int)k;   // rank remaining (1-based, from top)
  unsigned int t = 0;                     // threshold key prefix
  unsigned int mm = 0xFFFFu;              // per-thread match bitmask (16 elems)

  // ---- 4-pass radix-256 select (MSB first) for k-th largest key ----
  for (int pass = 0; pass < 4; ++pass) {
    const int shift = 24 - 8 * pass;
    hist[tid] = 0;
    __syncthreads();
#pragma unroll
    for (int e = 0; e < EPT; ++e) {
      if ((mm >> e) & 1u)
        atomicAdd(&hist[(key[e] >> shift) & 0xFFu], 1u);
    }
    __syncthreads();

    // suffix scan over 256 bins: incl(b) = # matched elems with bin >= b
    unsigned int h = hist[tid];
    unsigned int s = h;
#pragma unroll
    for (int off = 1; off < 64; off <<= 1) {
      unsigned int v = __shfl_down(s, off);
      if (lane + off < 64) s += v;
    }
    if (lane == 0) wtot[wv] = s;          // wave total (suffix within wave at lane0)
    __syncthreads();
#pragma unroll
    for (int w = 0; w < 4; ++w) {
      if (w > wv) s += wtot[w];
    }
    unsigned int incl = s;
    unsigned int excl = incl - h;         // # elems with bin > tid
    if (excl < k_rem && k_rem <= incl) {  // exactly one bin satisfies
      sh_selb  = (unsigned int)tid;
      sh_sexcl = excl;
    }
    __syncthreads();
    unsigned int selb = sh_selb;
    k_rem -= sh_sexcl;
    t |= selb << shift;
#pragma unroll
    for (int e = 0; e < EPT; ++e) {
      if (((key[e] >> shift) & 0xFFu) != selb) mm &= ~(1u << e);
    }
    __syncthreads();   // protect hist/wtot/sh_* before next pass reuse
  }

  // mm bit e now means key[e] == t exactly. r = k_rem equals must be kept,
  // in ascending element-index order (stable top-k tie behavior).
  const unsigned int r = k_rem;
  unsigned int cnt_eq = __popc(mm);
  if (tid == 0) sh_ce = 0;
  __syncthreads();
  if (cnt_eq) atomicAdd(&sh_ce, cnt_eq);
  __syncthreads();
  const unsigned int ce = sh_ce;

  const bool keepall = (r == ce);         // common case: keep every ==t elem
  unsigned int keepmask = 0;

  if (!keepall) {
    // rare: index-ordered selection of first r equals.
    // element index = 1024*j + 4*tid + c  -> order: j major, tid, then c.
    if (tid == 0) sh_run = 0;
    __syncthreads();
    for (int j = 0; j < VPT; ++j) {
      unsigned int cnt = (mm >> (4*j)) & 0xFu;
      cnt = __popc(cnt);
      // forward inclusive prefix scan across 256 threads (wave shfl + LDS)
      unsigned int p = cnt;
#pragma unroll
      for (int off = 1; off < 64; off <<= 1) {
        unsigned int v = __shfl_up(p, off);
        if (lane >= off) p += v;
      }
      if (lane == 63) wtot[wv] = p;
      __syncthreads();
      unsigned int woff = 0;
#pragma unroll
      for (int w = 0; w < 4; ++w) {
        if (w < wv) woff += wtot[w];
      }
      unsigned int runbase = sh_run;
      unsigned int mybase = runbase + woff + (p - cnt);   // eq-rank of first eq elem
#pragma unroll
      for (int c = 0; c < 4; ++c) {
        int e = 4*j + c;
        if ((mm >> e) & 1u) {
          if (mybase < r) keepmask |= (1u << e);
          mybase++;
        }
      }
      __syncthreads();
      if (tid == 0)
        sh_run = runbase + wtot[0] + wtot[1] + wtot[2] + wtot[3];
      __syncthreads();
    }
  }

  // ---- write output: x where kept, 0 elsewhere (coalesced float4) ----
  float4* ov = (float4*)(out + base);
#pragma unroll
  for (int j = 0; j < VPT; ++j) {
    float4 o;
    float* op = (float*)&o;
#pragma unroll
    for (int c = 0; c < 4; ++c) {
      int e = 4*j + c;
      unsigned int kk = key[e];
      bool keep = keepall ? (kk >= t)
                          : ((kk > t) || ((keepmask >> e) & 1u));
      op[c] = keep ? key2f(kk) : 0.0f;
    }
    ov[j * NT + tid] = o;
  }
}

extern "C" void kernel_launch(void* const* d_in, const int* in_sizes, int n_in,
                              void* d_out, int out_size, void* d_ws, size_t ws_size,
                              hipStream_t stream) {
  const float* x = (const float*)d_in[0];
  float* out = (float*)d_out;
  const int rows = in_sizes[0] / DIM;   // 4*4096 = 16384
  const int k = DIM / 2;                // TOPK==0 -> k = D/2
  topk_mask_kernel<<<rows, NT, 0, stream>>>(x, out, k);
}